// Round 10
// baseline (147.941 us; speedup 1.0000x reference)
//
#include <hip/hip_runtime.h>
#include <hip/hip_bf16.h>
#include <stdint.h>

#define NN 4096
#define DD 1024
// data scaled by 64 per matrix -> products x4096; logits = dot * 10
#define SCL (10.0f / 4096.0f)

typedef float f32x16 __attribute__((ext_vector_type(16)));
typedef int   i32x4  __attribute__((ext_vector_type(4)));
typedef int   i32x8  __attribute__((ext_vector_type(8)));

__device__ __forceinline__ void gload_lds16(const void* g, void* l) {
  __builtin_amdgcn_global_load_lds(
      (const __attribute__((address_space(1))) void*)g,
      (__attribute__((address_space(3))) void*)l, 16, 0, 0);
}

// ---------- kernel 1: row-L2-normalize -> fp8 e4m3 (x64), exact fp32 diagonal ----------
__global__ __launch_bounds__(256) void nrm_kernel(
    const float* __restrict__ e1, const float* __restrict__ e2,
    uint32_t* __restrict__ e1q, uint32_t* __restrict__ e2q,
    float* __restrict__ log_diag, float* __restrict__ exp_diag,
    float* __restrict__ row_sum, float* __restrict__ col_sum)
{
  const int row  = blockIdx.x;
  const int tid  = threadIdx.x;
  const int lane = tid & 63;
  const int wave = tid >> 6;
  const int64_t base = (int64_t)row * DD;

  const float4 v1 = *reinterpret_cast<const float4*>(e1 + base + tid * 4);
  const float4 v2 = *reinterpret_cast<const float4*>(e2 + base + tid * 4);

  float ss1 = v1.x*v1.x + v1.y*v1.y + v1.z*v1.z + v1.w*v1.w;
  float ss2 = v2.x*v2.x + v2.y*v2.y + v2.z*v2.z + v2.w*v2.w;
  float d12 = v1.x*v2.x + v1.y*v2.y + v1.z*v2.z + v1.w*v2.w;

  #pragma unroll
  for (int off = 1; off < 64; off <<= 1) {
    ss1 += __shfl_xor(ss1, off);
    ss2 += __shfl_xor(ss2, off);
    d12 += __shfl_xor(d12, off);
  }

  __shared__ float red[3][4];
  if (lane == 0) { red[0][wave] = ss1; red[1][wave] = ss2; red[2][wave] = d12; }
  __syncthreads();
  ss1 = red[0][0] + red[0][1] + red[0][2] + red[0][3];
  ss2 = red[1][0] + red[1][1] + red[1][2] + red[1][3];
  d12 = red[2][0] + red[2][1] + red[2][2] + red[2][3];

  const float inv1 = 1.0f / fmaxf(sqrtf(ss1), 1e-12f);
  const float inv2 = 1.0f / fmaxf(sqrtf(ss2), 1e-12f);

  if (tid == 0) {
    const float ld = d12 * inv1 * inv2 * 10.0f;
    log_diag[row] = ld;
    exp_diag[row] = __expf(ld);
    row_sum[row] = 0.0f;
    col_sum[row] = 0.0f;
  }

  const float s1 = inv1 * 64.0f;
  const float s2 = inv2 * 64.0f;
  int u1 = __builtin_amdgcn_cvt_pk_fp8_f32(v1.x * s1, v1.y * s1, 0, false);
  u1     = __builtin_amdgcn_cvt_pk_fp8_f32(v1.z * s1, v1.w * s1, u1, true);
  int u2 = __builtin_amdgcn_cvt_pk_fp8_f32(v2.x * s2, v2.y * s2, 0, false);
  u2     = __builtin_amdgcn_cvt_pk_fp8_f32(v2.z * s2, v2.w * s2, u2, true);
  e1q[row * (DD / 4) + tid] = (uint32_t)u1;
  e2q[row * (DD / 4) + tid] = (uint32_t)u2;
}

// ---------- kernel 2: fused MX-fp8 GEMM, 128x256 block, 64x128 wave tile ----------
// 4 waves (2M x 2N), 8 MFMA_scale_32x32x64/wave/tile (~550cy matrix work
// amortizes fixed per-tile latency). Triple-buffered LDS (72 KiB), prefetch
// distance 2 -> vmcnt(6) is a zero-stall counted wait (data issued 2 tiles
// earlier). 2 blocks/CU (launch_bounds(256,2): reg cap 256, 8 waves/CU).
// MX scales = 0x7F (1.0) -> bit-identical to plain fp8 (absmax 0.0, R7-R9).
__global__ __launch_bounds__(256, 2) void gemm_kernel(
    const uint8_t* __restrict__ A,   // e1q [NN][DD] fp8 bits (x64)
    const uint8_t* __restrict__ B,   // e2q [NN][DD] fp8 bits (x64)
    float* __restrict__ row_sum, float* __restrict__ col_sum)
{
  __shared__ __align__(16) uint8_t lds_a[3][128][64];   // 24 KiB
  __shared__ __align__(16) uint8_t lds_b[3][256][64];   // 48 KiB

  const int tid  = threadIdx.x;
  const int lane = tid & 63;
  const int wave = tid >> 6;          // 0..3
  const int wm = wave >> 1;           // 0..1 : rows [wm*64, +64)
  const int wn = wave & 1;            // 0..1 : cols [wn*128, +128)

  // XCD swizzle: grid 32x16 tiles; each XCD owns an 8x8 rectangle
  // (A 1 MB + B 2 MB = 3 MB < 4 MB per-XCD L2). 512 % 8 == 0 -> bijective.
  const int bid = blockIdx.x;
  const int xcd = bid & 7;
  const int k   = bid >> 3;           // 0..63
  const int brow = ((xcd >> 1) * 8 + (k >> 3)) * 128;
  const int bcol = ((xcd & 1) * 8 + (k & 7)) * 256;

  // fragment geometry (32x32x64): row = lane&31, k = (lane>>5)*32 + e
  const int r32 = lane & 31;
  const int h   = lane >> 5;
  const int cx  = (r32 >> 1) & 3;               // row-derived 16B-chunk XOR
  const int ch0 = ((h * 2)     ^ cx) * 16;      // byte offset, first 16B of frag
  const int ch1 = ((h * 2 + 1) ^ cx) * 16;      // second 16B

  // staging: lane l writes 16B chunk (l&3) of row (l>>2); source chunk
  // pre-swizzled by ((row>>1)&3) = ((l>>3)&3)  [same involution as read side]
  const int s_chunk = ((lane & 3) ^ ((lane >> 3) & 3)) * 16;
  const uint8_t* a_src0 = A + (int64_t)(brow + wave * 32 + (lane >> 2)) * DD + s_chunk;
  const uint8_t* a_src1 = a_src0 + 16 * DD;
  const uint8_t* b_src0 = B + (int64_t)(bcol + wave * 64 + (lane >> 2)) * DD + s_chunk;

  f32x16 acc00 = {}, acc01 = {}, acc02 = {}, acc03 = {};
  f32x16 acc10 = {}, acc11 = {}, acc12 = {}, acc13 = {};

#define STAGE(s, kc)                                               \
  gload_lds16(a_src0 + (kc), &lds_a[s][wave * 32][0]);             \
  gload_lds16(a_src1 + (kc), &lds_a[s][wave * 32 + 16][0]);        \
  gload_lds16(b_src0 + (kc),           &lds_b[s][wave * 64][0]);   \
  gload_lds16(b_src0 + 16 * DD + (kc), &lds_b[s][wave * 64 + 16][0]); \
  gload_lds16(b_src0 + 32 * DD + (kc), &lds_b[s][wave * 64 + 32][0]); \
  gload_lds16(b_src0 + 48 * DD + (kc), &lds_b[s][wave * 64 + 48][0]);

#define LOADFRAG(dst, ldsbuf, s, rbase)                                        \
  {                                                                            \
    const i32x4 lo_ = *reinterpret_cast<const i32x4*>(&ldsbuf[s][rbase][ch0]); \
    const i32x4 hi_ = *reinterpret_cast<const i32x4*>(&ldsbuf[s][rbase][ch1]); \
    dst = __builtin_shufflevector(lo_, hi_, 0, 1, 2, 3, 4, 5, 6, 7);           \
  }

#define MX(accv, avv, bvv)                                                     \
  accv = __builtin_amdgcn_mfma_scale_f32_32x32x64_f8f6f4(                      \
      avv, bvv, accv, 0, 0, 0, 0x7F7F7F7F, 0, 0x7F7F7F7F);

  // prologue: stage tiles 0 and 1 into slots 0 and 1 (12 gloads in flight)
  STAGE(0, 0)
  STAGE(1, 64)

  #pragma unroll
  for (int t = 0; t < 16; ++t) {
    const int s = t % 3;
    // slot s was staged 2 tiles ago; the 6 newer gloads (tile t+1) stay in flight
    if (t < 15) asm volatile("s_waitcnt vmcnt(6)" ::: "memory");
    else        asm volatile("s_waitcnt vmcnt(0)" ::: "memory");
    __builtin_amdgcn_s_barrier();

    i32x8 av0, av1, bv0, bv1, bv2, bv3;
    LOADFRAG(av0, lds_a, s, wm * 64 + r32)
    LOADFRAG(bv0, lds_b, s, wn * 128 + r32)
    LOADFRAG(av1, lds_a, s, wm * 64 + 32 + r32)
    LOADFRAG(bv1, lds_b, s, wn * 128 + 32 + r32)
    LOADFRAG(bv2, lds_b, s, wn * 128 + 64 + r32)
    LOADFRAG(bv3, lds_b, s, wn * 128 + 96 + r32)

    if (t <= 13) {
      const int sp = (t + 2) % 3;
      STAGE(sp, (t + 2) * 64)
    }

    __builtin_amdgcn_s_setprio(1);
    MX(acc00, av0, bv0)
    MX(acc10, av1, bv0)
    MX(acc01, av0, bv1)
    MX(acc11, av1, bv1)
    MX(acc02, av0, bv2)
    MX(acc12, av1, bv2)
    MX(acc03, av0, bv3)
    MX(acc13, av1, bv3)
    __builtin_amdgcn_s_setprio(0);
  }
#undef MX
#undef LOADFRAG
#undef STAGE

  // ---- fused epilogue: v = exp(SCL*acc); row & col partial sums ----
  // 32x32 C/D layout: col = lane&31, row = (r&3) + 8*(r>>2) + 4*(lane>>5)
  float colp0 = 0.0f, colp1 = 0.0f, colp2 = 0.0f, colp3 = 0.0f;

#define ROWSUM(A0, A1, A2, A3, RF)                                             \
  {                                                                            \
    _Pragma("unroll")                                                          \
    for (int r = 0; r < 16; ++r) {                                             \
      const float v0 = __expf((A0)[r] * SCL);                                  \
      const float v1 = __expf((A1)[r] * SCL);                                  \
      const float v2 = __expf((A2)[r] * SCL);                                  \
      const float v3 = __expf((A3)[r] * SCL);                                  \
      colp0 += v0; colp1 += v1; colp2 += v2; colp3 += v3;                      \
      float rr = (v0 + v1) + (v2 + v3);                                        \
      rr += __shfl_xor(rr, 1);                                                 \
      rr += __shfl_xor(rr, 2);                                                 \
      rr += __shfl_xor(rr, 4);                                                 \
      rr += __shfl_xor(rr, 8);                                                 \
      rr += __shfl_xor(rr, 16);                                                \
      if (r32 == 0) {                                                          \
        atomicAdd(&row_sum[brow + wm * 64 + (RF) * 32 +                        \
                           (r & 3) + 8 * (r >> 2) + 4 * h], rr);               \
      }                                                                        \
    }                                                                          \
  }

  ROWSUM(acc00, acc01, acc02, acc03, 0)
  ROWSUM(acc10, acc11, acc12, acc13, 1)
#undef ROWSUM

  // col sums: combine the two 32-lane halves (same col, disjoint rows)
#define COLSUM(CP, CI)                                                         \
  {                                                                            \
    float cc = (CP);                                                           \
    cc += __shfl_xor(cc, 32);                                                  \
    if (h == 0) atomicAdd(&col_sum[bcol + wn * 128 + (CI) * 32 + r32], cc);    \
  }
  COLSUM(colp0, 0)
  COLSUM(colp1, 1)
  COLSUM(colp2, 2)
  COLSUM(colp3, 3)
#undef COLSUM
}

// ---------- kernel 3: final scalar reduction (block 0 -> rows, block 1 -> cols) ----------
__global__ __launch_bounds__(1024) void fin_kernel(
    const float* __restrict__ row_sum, const float* __restrict__ col_sum,
    const float* __restrict__ log_diag, const float* __restrict__ exp_diag,
    float* __restrict__ out)
{
  const int tid  = threadIdx.x;
  const int lane = tid & 63;
  const int wave = tid >> 6;
  const float* sums = (blockIdx.x == 0) ? row_sum : col_sum;
  float a = 0.0f;
  #pragma unroll
  for (int kk = 0; kk < NN / 1024; ++kk) {
    const int i = tid + kk * 1024;
    a += logf(sums[i] - exp_diag[i]) - log_diag[i];
  }
  #pragma unroll
  for (int off = 1; off < 64; off <<= 1) a += __shfl_xor(a, off);
  __shared__ float r0[16];
  if (lane == 0) r0[wave] = a;
  __syncthreads();
  if (tid == 0) {
    float s = 0.0f;
    #pragma unroll
    for (int w = 0; w < 16; ++w) s += r0[w];
    out[blockIdx.x] = s;
  }
}

extern "C" void kernel_launch(void* const* d_in, const int* in_sizes, int n_in,
                              void* d_out, int out_size, void* d_ws, size_t ws_size,
                              hipStream_t stream) {
  const float* e1 = (const float*)d_in[0];
  const float* e2 = (const float*)d_in[1];
  float* out = (float*)d_out;

  char* ws = (char*)d_ws;
  uint32_t* e1q = (uint32_t*)ws;                                 // 4 MB (fp8)
  uint32_t* e2q = (uint32_t*)(ws + (size_t)NN * DD);             // 4 MB (fp8)
  float* log_diag = (float*)(ws + (size_t)NN * DD * 2);          // 16 KB
  float* exp_diag = log_diag + NN;                               // 16 KB
  float* row_sum  = exp_diag + NN;                               // 16 KB
  float* col_sum  = row_sum + NN;                                // 16 KB

  nrm_kernel<<<NN, 256, 0, stream>>>(e1, e2, e1q, e2q, log_diag, exp_diag,
                                     row_sum, col_sum);
  gemm_kernel<<<512, 256, 0, stream>>>((const uint8_t*)e1q, (const uint8_t*)e2q,
                                       row_sum, col_sum);
  fin_kernel<<<2, 1024, 0, stream>>>(row_sum, col_sum, log_diag, exp_diag, out);
}

// Round 11
// 119.631 us; speedup vs baseline: 1.2366x; 1.2366x over previous
//
#include <hip/hip_runtime.h>
#include <hip/hip_bf16.h>
#include <stdint.h>

#define NN 4096
#define DD 1024
// data scaled by 64 per matrix -> products x4096; logits = dot * 10
#define SCL (10.0f / 4096.0f)

typedef float f32x16 __attribute__((ext_vector_type(16)));
typedef int   i32x4  __attribute__((ext_vector_type(4)));
typedef int   i32x8  __attribute__((ext_vector_type(8)));

__device__ __forceinline__ void gload_lds16(const void* g, void* l) {
  __builtin_amdgcn_global_load_lds(
      (const __attribute__((address_space(1))) void*)g,
      (__attribute__((address_space(3))) void*)l, 16, 0, 0);
}

// ---------- kernel 1: row-L2-normalize -> fp8 e4m3 (x64), exact fp32 diagonal ----------
__global__ __launch_bounds__(256) void nrm_kernel(
    const float* __restrict__ e1, const float* __restrict__ e2,
    uint32_t* __restrict__ e1q, uint32_t* __restrict__ e2q,
    float* __restrict__ log_diag, float* __restrict__ exp_diag,
    float* __restrict__ row_sum, float* __restrict__ col_sum)
{
  const int row  = blockIdx.x;
  const int tid  = threadIdx.x;
  const int lane = tid & 63;
  const int wave = tid >> 6;
  const int64_t base = (int64_t)row * DD;

  const float4 v1 = *reinterpret_cast<const float4*>(e1 + base + tid * 4);
  const float4 v2 = *reinterpret_cast<const float4*>(e2 + base + tid * 4);

  float ss1 = v1.x*v1.x + v1.y*v1.y + v1.z*v1.z + v1.w*v1.w;
  float ss2 = v2.x*v2.x + v2.y*v2.y + v2.z*v2.z + v2.w*v2.w;
  float d12 = v1.x*v2.x + v1.y*v2.y + v1.z*v2.z + v1.w*v2.w;

  #pragma unroll
  for (int off = 1; off < 64; off <<= 1) {
    ss1 += __shfl_xor(ss1, off);
    ss2 += __shfl_xor(ss2, off);
    d12 += __shfl_xor(d12, off);
  }

  __shared__ float red[3][4];
  if (lane == 0) { red[0][wave] = ss1; red[1][wave] = ss2; red[2][wave] = d12; }
  __syncthreads();
  ss1 = red[0][0] + red[0][1] + red[0][2] + red[0][3];
  ss2 = red[1][0] + red[1][1] + red[1][2] + red[1][3];
  d12 = red[2][0] + red[2][1] + red[2][2] + red[2][3];

  const float inv1 = 1.0f / fmaxf(sqrtf(ss1), 1e-12f);
  const float inv2 = 1.0f / fmaxf(sqrtf(ss2), 1e-12f);

  if (tid == 0) {
    const float ld = d12 * inv1 * inv2 * 10.0f;
    log_diag[row] = ld;
    exp_diag[row] = __expf(ld);
    row_sum[row] = 0.0f;
    col_sum[row] = 0.0f;
  }

  const float s1 = inv1 * 64.0f;
  const float s2 = inv2 * 64.0f;
  int u1 = __builtin_amdgcn_cvt_pk_fp8_f32(v1.x * s1, v1.y * s1, 0, false);
  u1     = __builtin_amdgcn_cvt_pk_fp8_f32(v1.z * s1, v1.w * s1, u1, true);
  int u2 = __builtin_amdgcn_cvt_pk_fp8_f32(v2.x * s2, v2.y * s2, 0, false);
  u2     = __builtin_amdgcn_cvt_pk_fp8_f32(v2.z * s2, v2.w * s2, u2, true);
  e1q[row * (DD / 4) + tid] = (uint32_t)u1;
  e2q[row * (DD / 4) + tid] = (uint32_t)u2;
}

// ---------- kernel 2: fused MX-fp8 GEMM, 128x128 tile, quad-buffer, BK=128/phase ----------
// 4 waves (2M x 2N), wave 64x64, acc = 4 x f32x16 (R9-proven register-safe).
// 8 phases; each phase = 2 BK=64 slices = 8 MFMA/wave. Quad-buffered LDS
// (4 x 16 KiB slots), prefetch distance 2 phases -> vmcnt(8) counted wait
// (data issued ~1100 cy earlier). Slice-B ds_reads hidden under slice-A
// MFMAs via lgkmcnt(4)+sched_barrier. Slot restaged only after all-waves
// lgkmcnt(0)+barrier. MX scales 0x7F = 1.0 -> bit-identical math (absmax 0.0).
__global__ __launch_bounds__(256, 2) void gemm_kernel(
    const uint8_t* __restrict__ A,   // e1q [NN][DD] fp8 bits (x64)
    const uint8_t* __restrict__ B,   // e2q [NN][DD] fp8 bits (x64)
    float* __restrict__ row_sum, float* __restrict__ col_sum)
{
  __shared__ __align__(16) uint8_t lds_a[4][128][64];   // 32 KiB
  __shared__ __align__(16) uint8_t lds_b[4][128][64];   // 32 KiB

  const int tid  = threadIdx.x;
  const int lane = tid & 63;
  const int wave = tid >> 6;          // 0..3
  const int wm = wave >> 1;           // 0..1 : rows [wm*64, +64)
  const int wn = wave & 1;            // 0..1 : cols [wn*64, +64)

  // XCD swizzle: grid 32x32 tiles; each XCD owns an 8x16 rectangle
  // (A 1 MB + B 2 MB = 3 MB < 4 MB per-XCD L2). 1024 % 8 == 0 -> bijective.
  const int bid = blockIdx.x;
  const int xcd = bid & 7;
  const int k   = bid >> 3;           // 0..127
  const int brow = ((xcd >> 1) * 8 + (k >> 4)) * 128;
  const int bcol = ((xcd & 1) * 16 + (k & 15)) * 128;

  // fragment geometry (32x32x64): row = lane&31, k = (lane>>5)*32 + e
  const int r32 = lane & 31;
  const int h   = lane >> 5;
  const int cx  = (r32 >> 1) & 3;               // row-derived 16B-chunk XOR
  const int ch0 = ((h * 2)     ^ cx) * 16;      // byte offset, first 16B of frag
  const int ch1 = ((h * 2 + 1) ^ cx) * 16;      // second 16B

  // staging: lane l writes 16B chunk (l&3) of row (l>>2); source chunk
  // pre-swizzled by ((row>>1)&3) = ((l>>3)&3)  [same involution as read side]
  const int s_chunk = ((lane & 3) ^ ((lane >> 3) & 3)) * 16;
  const int s_row   = wave * 32 + (lane >> 2);
  const uint8_t* a_src0 = A + (int64_t)(brow + s_row) * DD + s_chunk;
  const uint8_t* a_src1 = a_src0 + 16 * DD;
  const uint8_t* b_src0 = B + (int64_t)(bcol + s_row) * DD + s_chunk;
  const uint8_t* b_src1 = b_src0 + 16 * DD;

  f32x16 acc00 = {}, acc01 = {}, acc10 = {}, acc11 = {};

// stage one K-tile (128 rows A + 128 rows B, 64 cols) into slot s; 4 gloads/thread
#define STAGE1(s, kc)                                          \
  gload_lds16(a_src0 + (kc), &lds_a[s][wave * 32][0]);         \
  gload_lds16(a_src1 + (kc), &lds_a[s][wave * 32 + 16][0]);    \
  gload_lds16(b_src0 + (kc), &lds_b[s][wave * 32][0]);         \
  gload_lds16(b_src1 + (kc), &lds_b[s][wave * 32 + 16][0]);

#define LOADFRAG(dst, ldsbuf, s, rbase)                                        \
  {                                                                            \
    const i32x4 lo_ = *reinterpret_cast<const i32x4*>(&ldsbuf[s][rbase][ch0]); \
    const i32x4 hi_ = *reinterpret_cast<const i32x4*>(&ldsbuf[s][rbase][ch1]); \
    dst = __builtin_shufflevector(lo_, hi_, 0, 1, 2, 3, 4, 5, 6, 7);           \
  }

#define MX(accv, avv, bvv)                                                     \
  accv = __builtin_amdgcn_mfma_scale_f32_32x32x64_f8f6f4(                      \
      avv, bvv, accv, 0, 0, 0, 0x7F7F7F7F, 0, 0x7F7F7F7F);

  // prologue: stage tiles 0..3 into slots 0..3 (16 gloads/thread in flight)
  STAGE1(0, 0)
  STAGE1(1, 64)
  STAGE1(2, 128)
  STAGE1(3, 192)

  #pragma unroll
  for (int p = 0; p < 8; ++p) {
    const int sA = (2 * p) & 3;        // slot of tile 2p
    const int sB = (2 * p + 1) & 3;    // slot of tile 2p+1

    // tiles 2p,2p+1 were staged 2 phases ago; 8 newer gloads stay in flight
    if (p < 7) asm volatile("s_waitcnt vmcnt(8)" ::: "memory");
    else       asm volatile("s_waitcnt vmcnt(0)" ::: "memory");
    __builtin_amdgcn_s_barrier();

    i32x8 aA0, aA1, bA0, bA1, aB0, aB1, bB0, bB1;
    LOADFRAG(aA0, lds_a, sA, wm * 64 + r32)
    LOADFRAG(bA0, lds_b, sA, wn * 64 + r32)
    LOADFRAG(aA1, lds_a, sA, wm * 64 + 32 + r32)
    LOADFRAG(bA1, lds_b, sA, wn * 64 + 32 + r32)
    LOADFRAG(aB0, lds_a, sB, wm * 64 + r32)
    LOADFRAG(bB0, lds_b, sB, wn * 64 + r32)
    LOADFRAG(aB1, lds_a, sB, wm * 64 + 32 + r32)
    LOADFRAG(bB1, lds_b, sB, wn * 64 + 32 + r32)

    // slice A ready (8 newer ds_reads of slice B in flight)
    asm volatile("s_waitcnt lgkmcnt(8)" ::: "memory");
    __builtin_amdgcn_sched_barrier(0);
    __builtin_amdgcn_s_setprio(1);
    MX(acc00, aA0, bA0)
    MX(acc01, aA0, bA1)
    MX(acc10, aA1, bA0)
    MX(acc11, aA1, bA1)

    // all own ds_reads done; barrier -> every wave's reads done -> slots free
    asm volatile("s_waitcnt lgkmcnt(0)" ::: "memory");
    __builtin_amdgcn_sched_barrier(0);
    __builtin_amdgcn_s_barrier();

    // restage the two just-freed slots with tiles 2p+4, 2p+5 (overlaps MFMA)
    if (p < 6) {
      STAGE1(sA, (2 * p + 4) * 64)
      STAGE1(sB, (2 * p + 5) * 64)
    }

    MX(acc00, aB0, bB0)
    MX(acc01, aB0, bB1)
    MX(acc10, aB1, bB0)
    MX(acc11, aB1, bB1)
    __builtin_amdgcn_s_setprio(0);
  }
#undef MX
#undef LOADFRAG
#undef STAGE1

  // ---- fused epilogue: v = exp(SCL*acc); row & col partial sums ----
  // 32x32 C/D layout: col = lane&31, row = (r&3) + 8*(r>>2) + 4*(lane>>5)
  float colp0 = 0.0f, colp1 = 0.0f;

#define ROWSUM(ACCL, ACCR, MI)                                                 \
  {                                                                            \
    _Pragma("unroll")                                                          \
    for (int r = 0; r < 16; ++r) {                                             \
      const float vL = __expf((ACCL)[r] * SCL);                                \
      const float vR = __expf((ACCR)[r] * SCL);                                \
      colp0 += vL;                                                             \
      colp1 += vR;                                                             \
      float rr = vL + vR;                                                      \
      rr += __shfl_xor(rr, 1);                                                 \
      rr += __shfl_xor(rr, 2);                                                 \
      rr += __shfl_xor(rr, 4);                                                 \
      rr += __shfl_xor(rr, 8);                                                 \
      rr += __shfl_xor(rr, 16);                                                \
      if (r32 == 0) {                                                          \
        atomicAdd(&row_sum[brow + wm * 64 + (MI) * 32 +                        \
                           (r & 3) + 8 * (r >> 2) + 4 * h], rr);               \
      }                                                                        \
    }                                                                          \
  }

  ROWSUM(acc00, acc01, 0)
  ROWSUM(acc10, acc11, 1)
#undef ROWSUM

  // col sums: combine the two 32-lane halves (same col, disjoint rows)
  {
    float cc = colp0;
    cc += __shfl_xor(cc, 32);
    if (h == 0) atomicAdd(&col_sum[bcol + wn * 64 + r32], cc);
  }
  {
    float cc = colp1;
    cc += __shfl_xor(cc, 32);
    if (h == 0) atomicAdd(&col_sum[bcol + wn * 64 + 32 + r32], cc);
  }
}

// ---------- kernel 3: final scalar reduction (block 0 -> rows, block 1 -> cols) ----------
__global__ __launch_bounds__(1024) void fin_kernel(
    const float* __restrict__ row_sum, const float* __restrict__ col_sum,
    const float* __restrict__ log_diag, const float* __restrict__ exp_diag,
    float* __restrict__ out)
{
  const int tid  = threadIdx.x;
  const int lane = tid & 63;
  const int wave = tid >> 6;
  const float* sums = (blockIdx.x == 0) ? row_sum : col_sum;
  float a = 0.0f;
  #pragma unroll
  for (int kk = 0; kk < NN / 1024; ++kk) {
    const int i = tid + kk * 1024;
    a += logf(sums[i] - exp_diag[i]) - log_diag[i];
  }
  #pragma unroll
  for (int off = 1; off < 64; off <<= 1) a += __shfl_xor(a, off);
  __shared__ float r0[16];
  if (lane == 0) r0[wave] = a;
  __syncthreads();
  if (tid == 0) {
    float s = 0.0f;
    #pragma unroll
    for (int w = 0; w < 16; ++w) s += r0[w];
    out[blockIdx.x] = s;
  }
}

extern "C" void kernel_launch(void* const* d_in, const int* in_sizes, int n_in,
                              void* d_out, int out_size, void* d_ws, size_t ws_size,
                              hipStream_t stream) {
  const float* e1 = (const float*)d_in[0];
  const float* e2 = (const float*)d_in[1];
  float* out = (float*)d_out;

  char* ws = (char*)d_ws;
  uint32_t* e1q = (uint32_t*)ws;                                 // 4 MB (fp8)
  uint32_t* e2q = (uint32_t*)(ws + (size_t)NN * DD);             // 4 MB (fp8)
  float* log_diag = (float*)(ws + (size_t)NN * DD * 2);          // 16 KB
  float* exp_diag = log_diag + NN;                               // 16 KB
  float* row_sum  = exp_diag + NN;                               // 16 KB
  float* col_sum  = row_sum + NN;                                // 16 KB

  nrm_kernel<<<NN, 256, 0, stream>>>(e1, e2, e1q, e2q, log_diag, exp_diag,
                                     row_sum, col_sum);
  gemm_kernel<<<1024, 256, 0, stream>>>((const uint8_t*)e1q, (const uint8_t*)e2q,
                                        row_sum, col_sum);
  fin_kernel<<<2, 1024, 0, stream>>>(row_sum, col_sum, log_diag, exp_diag, out);
}

// Round 12
// 69.251 us; speedup vs baseline: 2.1363x; 1.7275x over previous
//
#include <hip/hip_runtime.h>
#include <hip/hip_bf16.h>
#include <stdint.h>

#define NN 4096
#define DD 1024
// data scaled by 64 per matrix -> products x4096; logits = dot * 10
#define SCL (10.0f / 4096.0f)

typedef float f32x16 __attribute__((ext_vector_type(16)));
typedef int   i32x4  __attribute__((ext_vector_type(4)));
typedef int   i32x8  __attribute__((ext_vector_type(8)));

__device__ __forceinline__ void gload_lds16(const void* g, void* l) {
  __builtin_amdgcn_global_load_lds(
      (const __attribute__((address_space(1))) void*)g,
      (__attribute__((address_space(3))) void*)l, 16, 0, 0);
}

// ---------- kernel 1: row-L2-normalize -> fp8 e4m3 (x64), exact fp32 diagonal ----------
__global__ __launch_bounds__(256) void nrm_kernel(
    const float* __restrict__ e1, const float* __restrict__ e2,
    uint32_t* __restrict__ e1q, uint32_t* __restrict__ e2q,
    float* __restrict__ log_diag, float* __restrict__ exp_diag,
    float* __restrict__ row_sum, float* __restrict__ col_sum)
{
  const int row  = blockIdx.x;
  const int tid  = threadIdx.x;
  const int lane = tid & 63;
  const int wave = tid >> 6;
  const int64_t base = (int64_t)row * DD;

  const float4 v1 = *reinterpret_cast<const float4*>(e1 + base + tid * 4);
  const float4 v2 = *reinterpret_cast<const float4*>(e2 + base + tid * 4);

  float ss1 = v1.x*v1.x + v1.y*v1.y + v1.z*v1.z + v1.w*v1.w;
  float ss2 = v2.x*v2.x + v2.y*v2.y + v2.z*v2.z + v2.w*v2.w;
  float d12 = v1.x*v2.x + v1.y*v2.y + v1.z*v2.z + v1.w*v2.w;

  #pragma unroll
  for (int off = 1; off < 64; off <<= 1) {
    ss1 += __shfl_xor(ss1, off);
    ss2 += __shfl_xor(ss2, off);
    d12 += __shfl_xor(d12, off);
  }

  __shared__ float red[3][4];
  if (lane == 0) { red[0][wave] = ss1; red[1][wave] = ss2; red[2][wave] = d12; }
  __syncthreads();
  ss1 = red[0][0] + red[0][1] + red[0][2] + red[0][3];
  ss2 = red[1][0] + red[1][1] + red[1][2] + red[1][3];
  d12 = red[2][0] + red[2][1] + red[2][2] + red[2][3];

  const float inv1 = 1.0f / fmaxf(sqrtf(ss1), 1e-12f);
  const float inv2 = 1.0f / fmaxf(sqrtf(ss2), 1e-12f);

  if (tid == 0) {
    const float ld = d12 * inv1 * inv2 * 10.0f;
    log_diag[row] = ld;
    exp_diag[row] = __expf(ld);
    row_sum[row] = 0.0f;
    col_sum[row] = 0.0f;
  }

  const float s1 = inv1 * 64.0f;
  const float s2 = inv2 * 64.0f;
  int u1 = __builtin_amdgcn_cvt_pk_fp8_f32(v1.x * s1, v1.y * s1, 0, false);
  u1     = __builtin_amdgcn_cvt_pk_fp8_f32(v1.z * s1, v1.w * s1, u1, true);
  int u2 = __builtin_amdgcn_cvt_pk_fp8_f32(v2.x * s2, v2.y * s2, 0, false);
  u2     = __builtin_amdgcn_cvt_pk_fp8_f32(v2.z * s2, v2.w * s2, u2, true);
  e1q[row * (DD / 4) + tid] = (uint32_t)u1;
  e2q[row * (DD / 4) + tid] = (uint32_t)u2;
}

// ---------- kernel 2: fused MX-fp8 GEMM, 128x128 tile, BK=128/phase, 2 slices ----------
// Round-9-proven clean register shape: 4 x f32x16 acc (AGPR), <=8 i32x8 frags
// live (VGPR), partial unroll, ONE vmcnt(0)+barrier per phase. Each phase =
// two sequential BK=64 slices = 8 MFMA/wave (2x amortization vs R9-bench).
// Staging of tile t+1 split across phase t's halves -> drain distance 500+cy.
// LDS [2][2][128][64] x2 = 64 KiB -> 2 blocks/CU. MX scales 0x7F = 1.0 ->
// bit-identical to plain fp8 (absmax 0.0, verified R7-R11).
__global__ __launch_bounds__(256, 2) void gemm_kernel(
    const uint8_t* __restrict__ A,   // e1q [NN][DD] fp8 bits (x64)
    const uint8_t* __restrict__ B,   // e2q [NN][DD] fp8 bits (x64)
    float* __restrict__ row_sum, float* __restrict__ col_sum)
{
  __shared__ __align__(16) uint8_t lds_a[2][2][128][64];   // 32 KiB
  __shared__ __align__(16) uint8_t lds_b[2][2][128][64];   // 32 KiB

  const int tid  = threadIdx.x;
  const int lane = tid & 63;
  const int wave = tid >> 6;          // 0..3
  const int wm = wave >> 1;           // 0..1 : rows [wm*64, +64)
  const int wn = wave & 1;            // 0..1 : cols [wn*64, +64)

  // XCD swizzle: grid 32x32 tiles; each XCD owns an 8x16 rectangle
  // (A 1 MB + B 2 MB = 3 MB < 4 MB per-XCD L2). 1024 % 8 == 0 -> bijective.
  const int bid = blockIdx.x;
  const int xcd = bid & 7;
  const int k   = bid >> 3;           // 0..127
  const int brow = ((xcd >> 1) * 8 + (k >> 4)) * 128;
  const int bcol = ((xcd & 1) * 16 + (k & 15)) * 128;

  // fragment geometry (32x32x64): row = lane&31, k = (lane>>5)*32 + e
  const int r32 = lane & 31;
  const int h   = lane >> 5;
  const int cx  = (r32 >> 1) & 3;               // row-derived 16B-chunk XOR
  const int ch0 = ((h * 2)     ^ cx) * 16;      // byte offset, first 16B of frag
  const int ch1 = ((h * 2 + 1) ^ cx) * 16;      // second 16B

  // staging: lane l writes 16B chunk (l&3) of row (l>>2); source chunk
  // pre-swizzled by ((row>>1)&3) = ((l>>3)&3)  [same involution as read side]
  const int s_chunk = ((lane & 3) ^ ((lane >> 3) & 3)) * 16;
  const int s_row   = wave * 32 + (lane >> 2);
  const uint8_t* a_src0 = A + (int64_t)(brow + s_row) * DD + s_chunk;
  const uint8_t* a_src1 = a_src0 + 16 * DD;
  const uint8_t* b_src0 = B + (int64_t)(bcol + s_row) * DD + s_chunk;
  const uint8_t* b_src1 = b_src0 + 16 * DD;

  f32x16 acc00 = {}, acc01 = {}, acc10 = {}, acc11 = {};

// stage one BK=64 slice (128 rows A + 128 rows B) into [slot][kk]; 4 gloads
#define STAGE_SL(s, kk, kc)                                        \
  gload_lds16(a_src0 + (kc), &lds_a[s][kk][wave * 32][0]);         \
  gload_lds16(a_src1 + (kc), &lds_a[s][kk][wave * 32 + 16][0]);    \
  gload_lds16(b_src0 + (kc), &lds_b[s][kk][wave * 32][0]);         \
  gload_lds16(b_src1 + (kc), &lds_b[s][kk][wave * 32 + 16][0]);

#define LOADFRAG(dst, ldsbuf, s, kk, rbase)                                    \
  {                                                                            \
    const i32x4 lo_ =                                                          \
        *reinterpret_cast<const i32x4*>(&ldsbuf[s][kk][rbase][ch0]);           \
    const i32x4 hi_ =                                                          \
        *reinterpret_cast<const i32x4*>(&ldsbuf[s][kk][rbase][ch1]);           \
    dst = __builtin_shufflevector(lo_, hi_, 0, 1, 2, 3, 4, 5, 6, 7);           \
  }

#define MX(accv, avv, bvv)                                                     \
  accv = __builtin_amdgcn_mfma_scale_f32_32x32x64_f8f6f4(                      \
      avv, bvv, accv, 0, 0, 0, 0x7F7F7F7F, 0, 0x7F7F7F7F);

  // prologue: stage tile 0 (both slices) into slot 0 (8 gloads in flight)
  STAGE_SL(0, 0, 0)
  STAGE_SL(0, 1, 64)

  #pragma unroll 2
  for (int t = 0; t < 8; ++t) {       // 8 phases of BK=128
    const int c = t & 1;
    const int n = c ^ 1;
    const bool pf = (t < 7);
    const int kn = (t + 1) * 128;

    // both slices of tile t staged during phase t-1; all waves join barrier
    // after their own drain -> whole slot resident for everyone
    asm volatile("s_waitcnt vmcnt(0)" ::: "memory");
    __builtin_amdgcn_s_barrier();

    {  // ---- slice 0 ----
      i32x8 a0, a1, b0, b1;
      LOADFRAG(a0, lds_a, c, 0, wm * 64 + r32)
      LOADFRAG(b0, lds_b, c, 0, wn * 64 + r32)
      LOADFRAG(a1, lds_a, c, 0, wm * 64 + 32 + r32)
      LOADFRAG(b1, lds_b, c, 0, wn * 64 + 32 + r32)
      if (pf) { STAGE_SL(n, 0, kn) }
      __builtin_amdgcn_s_setprio(1);
      MX(acc00, a0, b0)
      MX(acc01, a0, b1)
      MX(acc10, a1, b0)
      MX(acc11, a1, b1)
      __builtin_amdgcn_s_setprio(0);
    }
    {  // ---- slice 1 (same slot c; covered by this phase's top barrier) ----
      i32x8 a0, a1, b0, b1;
      LOADFRAG(a0, lds_a, c, 1, wm * 64 + r32)
      LOADFRAG(b0, lds_b, c, 1, wn * 64 + r32)
      LOADFRAG(a1, lds_a, c, 1, wm * 64 + 32 + r32)
      LOADFRAG(b1, lds_b, c, 1, wn * 64 + 32 + r32)
      if (pf) { STAGE_SL(n, 1, kn + 64) }
      __builtin_amdgcn_s_setprio(1);
      MX(acc00, a0, b0)
      MX(acc01, a0, b1)
      MX(acc10, a1, b0)
      MX(acc11, a1, b1)
      __builtin_amdgcn_s_setprio(0);
    }
  }
#undef MX
#undef LOADFRAG
#undef STAGE_SL

  // ---- fused epilogue: v = exp(SCL*acc); row & col partial sums ----
  // 32x32 C/D layout: col = lane&31, row = (r&3) + 8*(r>>2) + 4*(lane>>5)
  float colp0 = 0.0f, colp1 = 0.0f;

#define ROWSUM(ACCL, ACCR, MI)                                                 \
  {                                                                            \
    _Pragma("unroll")                                                          \
    for (int r = 0; r < 16; ++r) {                                             \
      const float vL = __expf((ACCL)[r] * SCL);                                \
      const float vR = __expf((ACCR)[r] * SCL);                                \
      colp0 += vL;                                                             \
      colp1 += vR;                                                             \
      float rr = vL + vR;                                                      \
      rr += __shfl_xor(rr, 1);                                                 \
      rr += __shfl_xor(rr, 2);                                                 \
      rr += __shfl_xor(rr, 4);                                                 \
      rr += __shfl_xor(rr, 8);                                                 \
      rr += __shfl_xor(rr, 16);                                                \
      if (r32 == 0) {                                                          \
        atomicAdd(&row_sum[brow + wm * 64 + (MI) * 32 +                        \
                           (r & 3) + 8 * (r >> 2) + 4 * h], rr);               \
      }                                                                        \
    }                                                                          \
  }

  ROWSUM(acc00, acc01, 0)
  ROWSUM(acc10, acc11, 1)
#undef ROWSUM

  // col sums: combine the two 32-lane halves (same col, disjoint rows)
  {
    float cc = colp0;
    cc += __shfl_xor(cc, 32);
    if (h == 0) atomicAdd(&col_sum[bcol + wn * 64 + r32], cc);
  }
  {
    float cc = colp1;
    cc += __shfl_xor(cc, 32);
    if (h == 0) atomicAdd(&col_sum[bcol + wn * 64 + 32 + r32], cc);
  }
}

// ---------- kernel 3: final scalar reduction (block 0 -> rows, block 1 -> cols) ----------
__global__ __launch_bounds__(1024) void fin_kernel(
    const float* __restrict__ row_sum, const float* __restrict__ col_sum,
    const float* __restrict__ log_diag, const float* __restrict__ exp_diag,
    float* __restrict__ out)
{
  const int tid  = threadIdx.x;
  const int lane = tid & 63;
  const int wave = tid >> 6;
  const float* sums = (blockIdx.x == 0) ? row_sum : col_sum;
  float a = 0.0f;
  #pragma unroll
  for (int kk = 0; kk < NN / 1024; ++kk) {
    const int i = tid + kk * 1024;
    a += logf(sums[i] - exp_diag[i]) - log_diag[i];
  }
  #pragma unroll
  for (int off = 1; off < 64; off <<= 1) a += __shfl_xor(a, off);
  __shared__ float r0[16];
  if (lane == 0) r0[wave] = a;
  __syncthreads();
  if (tid == 0) {
    float s = 0.0f;
    #pragma unroll
    for (int w = 0; w < 16; ++w) s += r0[w];
    out[blockIdx.x] = s;
  }
}

extern "C" void kernel_launch(void* const* d_in, const int* in_sizes, int n_in,
                              void* d_out, int out_size, void* d_ws, size_t ws_size,
                              hipStream_t stream) {
  const float* e1 = (const float*)d_in[0];
  const float* e2 = (const float*)d_in[1];
  float* out = (float*)d_out;

  char* ws = (char*)d_ws;
  uint32_t* e1q = (uint32_t*)ws;                                 // 4 MB (fp8)
  uint32_t* e2q = (uint32_t*)(ws + (size_t)NN * DD);             // 4 MB (fp8)
  float* log_diag = (float*)(ws + (size_t)NN * DD * 2);          // 16 KB
  float* exp_diag = log_diag + NN;                               // 16 KB
  float* row_sum  = exp_diag + NN;                               // 16 KB
  float* col_sum  = row_sum + NN;                                // 16 KB

  nrm_kernel<<<NN, 256, 0, stream>>>(e1, e2, e1q, e2q, log_diag, exp_diag,
                                     row_sum, col_sum);
  gemm_kernel<<<1024, 256, 0, stream>>>((const uint8_t*)e1q, (const uint8_t*)e2q,
                                        row_sum, col_sum);
  fin_kernel<<<2, 1024, 0, stream>>>(row_sum, col_sum, log_diag, exp_diag, out);
}

// Round 13
// 62.834 us; speedup vs baseline: 2.3545x; 1.1021x over previous
//
#include <hip/hip_runtime.h>
#include <hip/hip_bf16.h>
#include <stdint.h>

#define NN 4096
#define DD 1024
// data scaled by 64 per matrix -> products x4096; logits = dot * 10
#define SCL (10.0f / 4096.0f)

typedef float f32x16 __attribute__((ext_vector_type(16)));
typedef int   i32x4  __attribute__((ext_vector_type(4)));
typedef int   i32x8  __attribute__((ext_vector_type(8)));

__device__ __forceinline__ void gload_lds16(const void* g, void* l) {
  __builtin_amdgcn_global_load_lds(
      (const __attribute__((address_space(1))) void*)g,
      (__attribute__((address_space(3))) void*)l, 16, 0, 0);
}

// ---------- kernel 1: row-L2-normalize -> fp8 e4m3 (x64), exact fp32 diagonal ----------
__global__ __launch_bounds__(256) void nrm_kernel(
    const float* __restrict__ e1, const float* __restrict__ e2,
    uint32_t* __restrict__ e1q, uint32_t* __restrict__ e2q,
    float* __restrict__ log_diag, float* __restrict__ exp_diag,
    float* __restrict__ row_sum, float* __restrict__ col_sum)
{
  const int row  = blockIdx.x;
  const int tid  = threadIdx.x;
  const int lane = tid & 63;
  const int wave = tid >> 6;
  const int64_t base = (int64_t)row * DD;

  const float4 v1 = *reinterpret_cast<const float4*>(e1 + base + tid * 4);
  const float4 v2 = *reinterpret_cast<const float4*>(e2 + base + tid * 4);

  float ss1 = v1.x*v1.x + v1.y*v1.y + v1.z*v1.z + v1.w*v1.w;
  float ss2 = v2.x*v2.x + v2.y*v2.y + v2.z*v2.z + v2.w*v2.w;
  float d12 = v1.x*v2.x + v1.y*v2.y + v1.z*v2.z + v1.w*v2.w;

  #pragma unroll
  for (int off = 1; off < 64; off <<= 1) {
    ss1 += __shfl_xor(ss1, off);
    ss2 += __shfl_xor(ss2, off);
    d12 += __shfl_xor(d12, off);
  }

  __shared__ float red[3][4];
  if (lane == 0) { red[0][wave] = ss1; red[1][wave] = ss2; red[2][wave] = d12; }
  __syncthreads();
  ss1 = red[0][0] + red[0][1] + red[0][2] + red[0][3];
  ss2 = red[1][0] + red[1][1] + red[1][2] + red[1][3];
  d12 = red[2][0] + red[2][1] + red[2][2] + red[2][3];

  const float inv1 = 1.0f / fmaxf(sqrtf(ss1), 1e-12f);
  const float inv2 = 1.0f / fmaxf(sqrtf(ss2), 1e-12f);

  if (tid == 0) {
    const float ld = d12 * inv1 * inv2 * 10.0f;
    log_diag[row] = ld;
    exp_diag[row] = __expf(ld);
    row_sum[row] = 0.0f;
    col_sum[row] = 0.0f;
  }

  const float s1 = inv1 * 64.0f;
  const float s2 = inv2 * 64.0f;
  int u1 = __builtin_amdgcn_cvt_pk_fp8_f32(v1.x * s1, v1.y * s1, 0, false);
  u1     = __builtin_amdgcn_cvt_pk_fp8_f32(v1.z * s1, v1.w * s1, u1, true);
  int u2 = __builtin_amdgcn_cvt_pk_fp8_f32(v2.x * s2, v2.y * s2, 0, false);
  u2     = __builtin_amdgcn_cvt_pk_fp8_f32(v2.z * s2, v2.w * s2, u2, true);
  e1q[row * (DD / 4) + tid] = (uint32_t)u1;
  e2q[row * (DD / 4) + tid] = (uint32_t)u2;
}

// ---------- kernel 2: fused MX-fp8 GEMM, 128x128 tile, ring-4 LDS, counted vmcnt ----------
// R12's clean register shape (4 x f32x16 acc, 4 frags live, partial unroll;
// VGPR 116, zero scratch) + the one missing lever: TRUE counted prefetch.
// Ring of 4 BK=64 slots (64 KiB -> 2 blocks/CU); prologue stages tiles 0..2;
// step t waits vmcnt(8) (tile t landed, 8 newer loads stay in flight, issued
// ~2.5 steps earlier), stages tile t+3. Barrier-per-step orders slot reuse
// (write at t targets slot last read at t-1). MX scales 0x7F = 1.0 ->
// bit-identical to plain fp8 (absmax 0.0, verified R7-R12).
__global__ __launch_bounds__(256, 2) void gemm_kernel(
    const uint8_t* __restrict__ A,   // e1q [NN][DD] fp8 bits (x64)
    const uint8_t* __restrict__ B,   // e2q [NN][DD] fp8 bits (x64)
    float* __restrict__ row_sum, float* __restrict__ col_sum)
{
  __shared__ __align__(16) uint8_t lds_a[4][128][64];   // 32 KiB
  __shared__ __align__(16) uint8_t lds_b[4][128][64];   // 32 KiB

  const int tid  = threadIdx.x;
  const int lane = tid & 63;
  const int wave = tid >> 6;          // 0..3
  const int wm = wave >> 1;           // 0..1 : rows [wm*64, +64)
  const int wn = wave & 1;            // 0..1 : cols [wn*64, +64)

  // XCD swizzle: grid 32x32 tiles; each XCD owns an 8x16 rectangle
  // (A 1 MB + B 2 MB = 3 MB < 4 MB per-XCD L2). 1024 % 8 == 0 -> bijective.
  const int bid = blockIdx.x;
  const int xcd = bid & 7;
  const int k   = bid >> 3;           // 0..127
  const int brow = ((xcd >> 1) * 8 + (k >> 4)) * 128;
  const int bcol = ((xcd & 1) * 16 + (k & 15)) * 128;

  // fragment geometry (32x32x64): row = lane&31, k = (lane>>5)*32 + e
  const int r32 = lane & 31;
  const int h   = lane >> 5;
  const int cx  = (r32 >> 1) & 3;               // row-derived 16B-chunk XOR
  const int ch0 = ((h * 2)     ^ cx) * 16;      // byte offset, first 16B of frag
  const int ch1 = ((h * 2 + 1) ^ cx) * 16;      // second 16B

  // staging: lane l writes 16B chunk (l&3) of row (l>>2); source chunk
  // pre-swizzled by ((row>>1)&3) = ((l>>3)&3)  [same involution as read side]
  const int s_chunk = ((lane & 3) ^ ((lane >> 3) & 3)) * 16;
  const int s_row   = wave * 32 + (lane >> 2);
  const uint8_t* a_src0 = A + (int64_t)(brow + s_row) * DD + s_chunk;
  const uint8_t* a_src1 = a_src0 + 16 * DD;
  const uint8_t* b_src0 = B + (int64_t)(bcol + s_row) * DD + s_chunk;
  const uint8_t* b_src1 = b_src0 + 16 * DD;

  f32x16 acc00 = {}, acc01 = {}, acc10 = {}, acc11 = {};

// stage one BK=64 tile (128 rows A + 128 rows B) into ring slot s; 4 gloads
#define STAGE1(s, kc)                                          \
  gload_lds16(a_src0 + (kc), &lds_a[s][wave * 32][0]);         \
  gload_lds16(a_src1 + (kc), &lds_a[s][wave * 32 + 16][0]);    \
  gload_lds16(b_src0 + (kc), &lds_b[s][wave * 32][0]);         \
  gload_lds16(b_src1 + (kc), &lds_b[s][wave * 32 + 16][0]);

#define LOADFRAG(dst, ldsbuf, s, rbase)                                        \
  {                                                                            \
    const i32x4 lo_ = *reinterpret_cast<const i32x4*>(&ldsbuf[s][rbase][ch0]); \
    const i32x4 hi_ = *reinterpret_cast<const i32x4*>(&ldsbuf[s][rbase][ch1]); \
    dst = __builtin_shufflevector(lo_, hi_, 0, 1, 2, 3, 4, 5, 6, 7);           \
  }

#define MX(accv, avv, bvv)                                                     \
  accv = __builtin_amdgcn_mfma_scale_f32_32x32x64_f8f6f4(                      \
      avv, bvv, accv, 0, 0, 0, 0x7F7F7F7F, 0, 0x7F7F7F7F);

// one ring step: read slot S, optionally stage tile into slot (S+3)&3
#define BODY(S, PF, KC)                                        \
  {                                                            \
    i32x8 a0, a1, b0, b1;                                      \
    LOADFRAG(a0, lds_a, S, wm * 64 + r32)                      \
    LOADFRAG(b0, lds_b, S, wn * 64 + r32)                      \
    LOADFRAG(a1, lds_a, S, wm * 64 + 32 + r32)                 \
    LOADFRAG(b1, lds_b, S, wn * 64 + 32 + r32)                 \
    if (PF) { STAGE1(((S) + 3) & 3, KC) }                      \
    __builtin_amdgcn_s_setprio(1);                             \
    MX(acc00, a0, b0)                                          \
    MX(acc01, a0, b1)                                          \
    MX(acc10, a1, b0)                                          \
    MX(acc11, a1, b1)                                          \
    __builtin_amdgcn_s_setprio(0);                             \
  }

  // prologue: stage tiles 0,1,2 into slots 0,1,2 (12 gloads in flight)
  STAGE1(0, 0)
  STAGE1(1, 64)
  STAGE1(2, 128)

  // steady state: tiles t+1, t+2 (8 loads) remain in flight across the wait
  #pragma unroll 4
  for (int t = 0; t < 12; ++t) {
    asm volatile("s_waitcnt vmcnt(8)" ::: "memory");
    __builtin_amdgcn_s_barrier();
    BODY(t & 3, true, (t + 3) * 64)
  }
  // t = 12: stage the last tile (15)
  asm volatile("s_waitcnt vmcnt(8)" ::: "memory");
  __builtin_amdgcn_s_barrier();
  BODY(0, true, 15 * 64)
  // t = 13
  asm volatile("s_waitcnt vmcnt(8)" ::: "memory");
  __builtin_amdgcn_s_barrier();
  BODY(1, false, 0)
  // t = 14
  asm volatile("s_waitcnt vmcnt(4)" ::: "memory");
  __builtin_amdgcn_s_barrier();
  BODY(2, false, 0)
  // t = 15
  asm volatile("s_waitcnt vmcnt(0)" ::: "memory");
  __builtin_amdgcn_s_barrier();
  BODY(3, false, 0)

#undef BODY
#undef MX
#undef LOADFRAG
#undef STAGE1

  // ---- fused epilogue: v = exp(SCL*acc); row & col partial sums ----
  // 32x32 C/D layout: col = lane&31, row = (r&3) + 8*(r>>2) + 4*(lane>>5)
  float colp0 = 0.0f, colp1 = 0.0f;

#define ROWSUM(ACCL, ACCR, MI)                                                 \
  {                                                                            \
    _Pragma("unroll")                                                          \
    for (int r = 0; r < 16; ++r) {                                             \
      const float vL = __expf((ACCL)[r] * SCL);                                \
      const float vR = __expf((ACCR)[r] * SCL);                                \
      colp0 += vL;                                                             \
      colp1 += vR;                                                             \
      float rr = vL + vR;                                                      \
      rr += __shfl_xor(rr, 1);                                                 \
      rr += __shfl_xor(rr, 2);                                                 \
      rr += __shfl_xor(rr, 4);                                                 \
      rr += __shfl_xor(rr, 8);                                                 \
      rr += __shfl_xor(rr, 16);                                                \
      if (r32 == 0) {                                                          \
        atomicAdd(&row_sum[brow + wm * 64 + (MI) * 32 +                        \
                           (r & 3) + 8 * (r >> 2) + 4 * h], rr);               \
      }                                                                        \
    }                                                                          \
  }

  ROWSUM(acc00, acc01, 0)
  ROWSUM(acc10, acc11, 1)
#undef ROWSUM

  // col sums: combine the two 32-lane halves (same col, disjoint rows)
  {
    float cc = colp0;
    cc += __shfl_xor(cc, 32);
    if (h == 0) atomicAdd(&col_sum[bcol + wn * 64 + r32], cc);
  }
  {
    float cc = colp1;
    cc += __shfl_xor(cc, 32);
    if (h == 0) atomicAdd(&col_sum[bcol + wn * 64 + 32 + r32], cc);
  }
}

// ---------- kernel 3: final scalar reduction (block 0 -> rows, block 1 -> cols) ----------
__global__ __launch_bounds__(1024) void fin_kernel(
    const float* __restrict__ row_sum, const float* __restrict__ col_sum,
    const float* __restrict__ log_diag, const float* __restrict__ exp_diag,
    float* __restrict__ out)
{
  const int tid  = threadIdx.x;
  const int lane = tid & 63;
  const int wave = tid >> 6;
  const float* sums = (blockIdx.x == 0) ? row_sum : col_sum;
  float a = 0.0f;
  #pragma unroll
  for (int kk = 0; kk < NN / 1024; ++kk) {
    const int i = tid + kk * 1024;
    a += logf(sums[i] - exp_diag[i]) - log_diag[i];
  }
  #pragma unroll
  for (int off = 1; off < 64; off <<= 1) a += __shfl_xor(a, off);
  __shared__ float r0[16];
  if (lane == 0) r0[wave] = a;
  __syncthreads();
  if (tid == 0) {
    float s = 0.0f;
    #pragma unroll
    for (int w = 0; w < 16; ++w) s += r0[w];
    out[blockIdx.x] = s;
  }
}

extern "C" void kernel_launch(void* const* d_in, const int* in_sizes, int n_in,
                              void* d_out, int out_size, void* d_ws, size_t ws_size,
                              hipStream_t stream) {
  const float* e1 = (const float*)d_in[0];
  const float* e2 = (const float*)d_in[1];
  float* out = (float*)d_out;

  char* ws = (char*)d_ws;
  uint32_t* e1q = (uint32_t*)ws;                                 // 4 MB (fp8)
  uint32_t* e2q = (uint32_t*)(ws + (size_t)NN * DD);             // 4 MB (fp8)
  float* log_diag = (float*)(ws + (size_t)NN * DD * 2);          // 16 KB
  float* exp_diag = log_diag + NN;                               // 16 KB
  float* row_sum  = exp_diag + NN;                               // 16 KB
  float* col_sum  = row_sum + NN;                                // 16 KB

  nrm_kernel<<<NN, 256, 0, stream>>>(e1, e2, e1q, e2q, log_diag, exp_diag,
                                     row_sum, col_sum);
  gemm_kernel<<<1024, 256, 0, stream>>>((const uint8_t*)e1q, (const uint8_t*)e2q,
                                        row_sum, col_sum);
  fin_kernel<<<2, 1024, 0, stream>>>(row_sum, col_sum, log_diag, exp_diag, out);
}

// Round 14
// 52.294 us; speedup vs baseline: 2.8290x; 1.2016x over previous
//
#include <hip/hip_runtime.h>
#include <hip/hip_bf16.h>
#include <stdint.h>

#define NN 4096
#define DD 1024
// data scaled by 64 per matrix -> products x4096; logits = dot * 10
#define SCL (10.0f / 4096.0f)

typedef float f32x4 __attribute__((ext_vector_type(4)));
typedef long long i64;

__device__ __forceinline__ void gload_lds16(const void* g, void* l) {
  __builtin_amdgcn_global_load_lds(
      (const __attribute__((address_space(1))) void*)g,
      (__attribute__((address_space(3))) void*)l, 16, 0, 0);
}

// ---------- kernel 1: row-L2-normalize -> fp8 e4m3 (x64), exact fp32 diagonal ----------
__global__ __launch_bounds__(256) void nrm_kernel(
    const float* __restrict__ e1, const float* __restrict__ e2,
    uint32_t* __restrict__ e1q, uint32_t* __restrict__ e2q,
    float* __restrict__ log_diag, float* __restrict__ exp_diag,
    float* __restrict__ row_sum, float* __restrict__ col_sum)
{
  const int row  = blockIdx.x;
  const int tid  = threadIdx.x;
  const int lane = tid & 63;
  const int wave = tid >> 6;
  const int64_t base = (int64_t)row * DD;

  const float4 v1 = *reinterpret_cast<const float4*>(e1 + base + tid * 4);
  const float4 v2 = *reinterpret_cast<const float4*>(e2 + base + tid * 4);

  float ss1 = v1.x*v1.x + v1.y*v1.y + v1.z*v1.z + v1.w*v1.w;
  float ss2 = v2.x*v2.x + v2.y*v2.y + v2.z*v2.z + v2.w*v2.w;
  float d12 = v1.x*v2.x + v1.y*v2.y + v1.z*v2.z + v1.w*v2.w;

  #pragma unroll
  for (int off = 1; off < 64; off <<= 1) {
    ss1 += __shfl_xor(ss1, off);
    ss2 += __shfl_xor(ss2, off);
    d12 += __shfl_xor(d12, off);
  }

  __shared__ float red[3][4];
  if (lane == 0) { red[0][wave] = ss1; red[1][wave] = ss2; red[2][wave] = d12; }
  __syncthreads();
  ss1 = red[0][0] + red[0][1] + red[0][2] + red[0][3];
  ss2 = red[1][0] + red[1][1] + red[1][2] + red[1][3];
  d12 = red[2][0] + red[2][1] + red[2][2] + red[2][3];

  const float inv1 = 1.0f / fmaxf(sqrtf(ss1), 1e-12f);
  const float inv2 = 1.0f / fmaxf(sqrtf(ss2), 1e-12f);

  if (tid == 0) {
    const float ld = d12 * inv1 * inv2 * 10.0f;
    log_diag[row] = ld;
    exp_diag[row] = __expf(ld);
    row_sum[row] = 0.0f;
    col_sum[row] = 0.0f;
  }

  const float s1 = inv1 * 64.0f;
  const float s2 = inv2 * 64.0f;
  int u1 = __builtin_amdgcn_cvt_pk_fp8_f32(v1.x * s1, v1.y * s1, 0, false);
  u1     = __builtin_amdgcn_cvt_pk_fp8_f32(v1.z * s1, v1.w * s1, u1, true);
  int u2 = __builtin_amdgcn_cvt_pk_fp8_f32(v2.x * s2, v2.y * s2, 0, false);
  u2     = __builtin_amdgcn_cvt_pk_fp8_f32(v2.z * s2, v2.w * s2, u2, true);
  e1q[row * (DD / 4) + tid] = (uint32_t)u1;
  e2q[row * (DD / 4) + tid] = (uint32_t)u2;
}

// ---------- kernel 2: fused fp8 GEMM, 256x256 tile, 8 waves, ring-3, counted vmcnt ----------
// Port of the verified 8-phase 256-square schedule to fp8 e4m3 16x16x32:
// same MFMA count as bf16, half the LDS/staging bytes -> ring-3 fits 96 KiB.
// 8 waves (2M x 4N), wave tile 128x64, acc[8][4] f32x4 (R2/R3-proven clean).
// Per K-tile (BK=64): 4 phases x 16 MFMA, ds_reads + 1 stage-gload per phase,
// ONE {vmcnt(4); s_barrier} per K-tile (stage distance 2 tiles ~2000cy ->
// true counted wait). Compiler handles ds_read->MFMA lgkm waits (m97).
__global__ __launch_bounds__(512, 2) void gemm_kernel(
    const uint8_t* __restrict__ A,   // e1q [NN][DD] fp8 bits (x64)
    const uint8_t* __restrict__ B,   // e2q [NN][DD] fp8 bits (x64)
    float* __restrict__ row_sum, float* __restrict__ col_sum)
{
  __shared__ __align__(16) uint8_t lds_a[3][256][64];   // 48 KiB
  __shared__ __align__(16) uint8_t lds_b[3][256][64];   // 48 KiB

  const int tid  = threadIdx.x;
  const int lane = tid & 63;
  const int wave = tid >> 6;          // 0..7
  const int wm = wave >> 2;           // 0..1 : rows [wm*128, +128)
  const int wn = wave & 3;            // 0..3 : cols [wn*64, +64)

  // XCD swizzle: 16x16 tile grid, 256 blocks = 1/CU; each XCD owns 4x8 rect
  const int bid = blockIdx.x;
  const int xcd = bid & 7;
  const int k   = bid >> 3;           // 0..31
  const int brow = ((xcd >> 1) * 4 + (k >> 3)) * 256;
  const int bcol = ((xcd & 1) * 8 + (k & 7)) * 256;

  // fragment geometry (16x16x32 fp8): row = lane&15, k-bytes = kk*32 + fq*8
  const int fr  = lane & 15;
  const int fq  = lane >> 4;          // 0..3
  const int fq1 = fq & 1;
  const int fq2 = fq >> 1;
  const int frx = (fr >> 1) & 3;      // row-derived 16B-chunk XOR
  const int o0  = ((fq2 ^ frx) << 4) + (fq1 << 3);   // kk=0 byte offset
  const int o1  = o0 ^ 32;                           // kk=1 (chunk XOR 2)

  // staging: lane l writes 16B chunk (l&3) of row (l>>2); source chunk
  // pre-swizzled by ((row>>1)&3) = ((l>>3)&3)  [same involution as read side]
  const int s_chunk = ((lane & 3) ^ ((lane >> 3) & 3)) * 16;
  const int s_row   = wave * 16 + (lane >> 2);
  const uint8_t* a_src0 = A + (int64_t)(brow + s_row) * DD + s_chunk;
  const uint8_t* a_src1 = a_src0 + 128 * DD;
  const uint8_t* b_src0 = B + (int64_t)(bcol + s_row) * DD + s_chunk;
  const uint8_t* b_src1 = b_src0 + 128 * DD;

  f32x4 acc[8][4] = {};

#define ST_A0(s, kc) gload_lds16(a_src0 + (kc), &lds_a[s][wave * 16][0]);
#define ST_A1(s, kc) gload_lds16(a_src1 + (kc), &lds_a[s][128 + wave * 16][0]);
#define ST_B0(s, kc) gload_lds16(b_src0 + (kc), &lds_b[s][wave * 16][0]);
#define ST_B1(s, kc) gload_lds16(b_src1 + (kc), &lds_b[s][128 + wave * 16][0]);

#define LDA(S, m, O) \
  (*reinterpret_cast<const i64*>(&lds_a[S][wm * 128 + (m) * 16 + fr][O]))
#define LDB(S, n, O) \
  (*reinterpret_cast<const i64*>(&lds_b[S][wn * 64 + (n) * 16 + fr][O]))

#define MF(m, n, av, bv)                                           \
  acc[m][n] = __builtin_amdgcn_mfma_f32_16x16x32_fp8_fp8(          \
      av, bv, acc[m][n], 0, 0, 0);

#define MF16(MB, A0, A1, A2, A3)                                   \
  MF(MB + 0, 0, A0, b0) MF(MB + 0, 1, A0, b1)                      \
  MF(MB + 0, 2, A0, b2) MF(MB + 0, 3, A0, b3)                      \
  MF(MB + 1, 0, A1, b0) MF(MB + 1, 1, A1, b1)                      \
  MF(MB + 1, 2, A1, b2) MF(MB + 1, 3, A1, b3)                      \
  MF(MB + 2, 0, A2, b0) MF(MB + 2, 1, A2, b1)                      \
  MF(MB + 2, 2, A2, b2) MF(MB + 2, 3, A2, b3)                      \
  MF(MB + 3, 0, A3, b0) MF(MB + 3, 1, A3, b1)                      \
  MF(MB + 3, 2, A3, b2) MF(MB + 3, 3, A3, b3)

// one K-tile = 4 phases; reads slot S, stages tile into slot (S+2)%3
#define TILE(S, PF, KC)                                                      \
  {                                                                          \
    const int SP = ((S) + 2) % 3;                                            \
    i64 b0, b1, b2, b3, a0, a1, a2, a3;                                      \
    /* phase 1: kk0, mh0 */                                                  \
    b0 = LDB(S, 0, o0); b1 = LDB(S, 1, o0);                                  \
    b2 = LDB(S, 2, o0); b3 = LDB(S, 3, o0);                                  \
    a0 = LDA(S, 0, o0); a1 = LDA(S, 1, o0);                                  \
    a2 = LDA(S, 2, o0); a3 = LDA(S, 3, o0);                                  \
    if (PF) { ST_A0(SP, KC) }                                                \
    __builtin_amdgcn_s_setprio(1);                                           \
    MF16(0, a0, a1, a2, a3)                                                  \
    __builtin_amdgcn_s_setprio(0);                                           \
    /* phase 2: kk0, mh1 (reuse b0..b3) */                                   \
    a0 = LDA(S, 4, o0); a1 = LDA(S, 5, o0);                                  \
    a2 = LDA(S, 6, o0); a3 = LDA(S, 7, o0);                                  \
    if (PF) { ST_A1(SP, KC) }                                                \
    __builtin_amdgcn_s_setprio(1);                                           \
    MF16(4, a0, a1, a2, a3)                                                  \
    __builtin_amdgcn_s_setprio(0);                                           \
    /* phase 3: kk1, mh0 */                                                  \
    b0 = LDB(S, 0, o1); b1 = LDB(S, 1, o1);                                  \
    b2 = LDB(S, 2, o1); b3 = LDB(S, 3, o1);                                  \
    a0 = LDA(S, 0, o1); a1 = LDA(S, 1, o1);                                  \
    a2 = LDA(S, 2, o1); a3 = LDA(S, 3, o1);                                  \
    if (PF) { ST_B0(SP, KC) }                                                \
    __builtin_amdgcn_s_setprio(1);                                           \
    MF16(0, a0, a1, a2, a3)                                                  \
    __builtin_amdgcn_s_setprio(0);                                           \
    /* phase 4: kk1, mh1 (reuse b0..b3) */                                   \
    a0 = LDA(S, 4, o1); a1 = LDA(S, 5, o1);                                  \
    a2 = LDA(S, 6, o1); a3 = LDA(S, 7, o1);                                  \
    if (PF) { ST_B1(SP, KC) }                                                \
    __builtin_amdgcn_s_setprio(1);                                           \
    MF16(4, a0, a1, a2, a3)                                                  \
    __builtin_amdgcn_s_setprio(0);                                           \
  }

  // prologue: stage tiles 0 and 1 into slots 0 and 1 (8 gloads in flight)
  ST_A0(0, 0) ST_A1(0, 0) ST_B0(0, 0) ST_B1(0, 0)
  ST_A0(1, 64) ST_A1(1, 64) ST_B0(1, 64) ST_B1(1, 64)

  // steady state: at top of tile t, stage(t) is the oldest 4 of <=8 in
  // flight; stage(t+1) (4 loads, issued during t-1) stays in flight.
  #pragma unroll 3
  for (int t = 0; t < 15; ++t) {
    asm volatile("s_waitcnt vmcnt(4)\n\ts_barrier" ::: "memory");
    TILE(t % 3, (t <= 13), (t + 2) * 64)
  }
  // tile 15 (slot 0): drain everything
  asm volatile("s_waitcnt vmcnt(0)\n\ts_barrier" ::: "memory");
  TILE(0, false, 0)

#undef TILE
#undef MF16
#undef MF
#undef LDB
#undef LDA
#undef ST_B1
#undef ST_B0
#undef ST_A1
#undef ST_A0

  // ---- fused epilogue: v = exp(SCL*acc); row & col partial sums ----
  // 16x16 C/D layout: col = fr, row = fq*4 + j (within each fragment)
  float rowp[8][4];
  float colp[4];
  #pragma unroll
  for (int mi = 0; mi < 8; ++mi)
    #pragma unroll
    for (int j = 0; j < 4; ++j) rowp[mi][j] = 0.0f;
  #pragma unroll
  for (int ni = 0; ni < 4; ++ni) colp[ni] = 0.0f;

  #pragma unroll
  for (int mi = 0; mi < 8; ++mi) {
    #pragma unroll
    for (int ni = 0; ni < 4; ++ni) {
      #pragma unroll
      for (int j = 0; j < 4; ++j) {
        const float v = __expf(acc[mi][ni][j] * SCL);
        rowp[mi][j] += v;
        colp[ni]    += v;
      }
    }
  }

  // row sums: reduce across 16 col-lanes, 1 atomic per row per wave
  #pragma unroll
  for (int mi = 0; mi < 8; ++mi) {
    #pragma unroll
    for (int j = 0; j < 4; ++j) {
      float r = rowp[mi][j];
      r += __shfl_xor(r, 1);
      r += __shfl_xor(r, 2);
      r += __shfl_xor(r, 4);
      r += __shfl_xor(r, 8);
      if (fr == 0) {
        atomicAdd(&row_sum[brow + wm * 128 + mi * 16 + fq * 4 + j], r);
      }
    }
  }
  // col sums: reduce across the 4 fq row-groups, 1 atomic per col per wave
  #pragma unroll
  for (int ni = 0; ni < 4; ++ni) {
    float cc = colp[ni];
    cc += __shfl_xor(cc, 16);
    cc += __shfl_xor(cc, 32);
    if (lane < 16) {
      atomicAdd(&col_sum[bcol + wn * 64 + ni * 16 + fr], cc);
    }
  }
}

// ---------- kernel 3: final scalar reduction (block 0 -> rows, block 1 -> cols) ----------
__global__ __launch_bounds__(1024) void fin_kernel(
    const float* __restrict__ row_sum, const float* __restrict__ col_sum,
    const float* __restrict__ log_diag, const float* __restrict__ exp_diag,
    float* __restrict__ out)
{
  const int tid  = threadIdx.x;
  const int lane = tid & 63;
  const int wave = tid >> 6;
  const float* sums = (blockIdx.x == 0) ? row_sum : col_sum;
  float a = 0.0f;
  #pragma unroll
  for (int kk = 0; kk < NN / 1024; ++kk) {
    const int i = tid + kk * 1024;
    a += logf(sums[i] - exp_diag[i]) - log_diag[i];
  }
  #pragma unroll
  for (int off = 1; off < 64; off <<= 1) a += __shfl_xor(a, off);
  __shared__ float r0[16];
  if (lane == 0) r0[wave] = a;
  __syncthreads();
  if (tid == 0) {
    float s = 0.0f;
    #pragma unroll
    for (int w = 0; w < 16; ++w) s += r0[w];
    out[blockIdx.x] = s;
  }
}

extern "C" void kernel_launch(void* const* d_in, const int* in_sizes, int n_in,
                              void* d_out, int out_size, void* d_ws, size_t ws_size,
                              hipStream_t stream) {
  const float* e1 = (const float*)d_in[0];
  const float* e2 = (const float*)d_in[1];
  float* out = (float*)d_out;

  char* ws = (char*)d_ws;
  uint32_t* e1q = (uint32_t*)ws;                                 // 4 MB (fp8)
  uint32_t* e2q = (uint32_t*)(ws + (size_t)NN * DD);             // 4 MB (fp8)
  float* log_diag = (float*)(ws + (size_t)NN * DD * 2);          // 16 KB
  float* exp_diag = log_diag + NN;                               // 16 KB
  float* row_sum  = exp_diag + NN;                               // 16 KB
  float* col_sum  = row_sum + NN;                                // 16 KB

  nrm_kernel<<<NN, 256, 0, stream>>>(e1, e2, e1q, e2q, log_diag, exp_diag,
                                     row_sum, col_sum);
  gemm_kernel<<<256, 512, 0, stream>>>((const uint8_t*)e1q, (const uint8_t*)e2q,
                                       row_sum, col_sum);
  fin_kernel<<<2, 1024, 0, stream>>>(row_sum, col_sum, log_diag, exp_diag, out);
}